// Round 1
// baseline (283.477 us; speedup 1.0000x reference)
//
#include <hip/hip_runtime.h>
#include <math.h>

// ---------------------------------------------------------------------------
// DualVSSEncoder: B=2, IN_C=64, OUT_C=128, H0=W0=128 -> pooled 64x64 (L=4096)
// D_INNER=256, D_STATE=8, DT_RANK=8, K_DIRS=2
// Strategy: 11 small kernels; chunked parallel scan (NC=128 chunks of 32).
// ---------------------------------------------------------------------------

#define LTOT 4096   // H*W after pool (64*64)
#define DI   256
#define NST  8
#define NC   128    // chunks
#define CS   32     // chunk size (NC*CS = LTOT)

static __device__ __forceinline__ float sigm_(float x){ return 1.f/(1.f+__expf(-x)); }
static __device__ __forceinline__ float softplus_(float x){
    return fmaxf(x, 0.f) + log1pf(__expf(-fabsf(x)));
}

// ---- maxpool 2x2: x[2,64,128,128] -> pooled[2,64,64,64] -------------------
__global__ __launch_bounds__(256) void k_pool(const float* __restrict__ x,
                                              float* __restrict__ pooled){
    int t = blockIdx.x*256 + threadIdx.x;          // 0..524287
    int j = t & 63, i = (t>>6) & 63, c = (t>>12) & 63, b = t>>18;
    const float* p = x + (((b*64 + c)*128 + 2*i)*128 + 2*j);
    pooled[t] = fmaxf(fmaxf(p[0], p[1]), fmaxf(p[128], p[129]));
}

// ---- 1x1 conv + BN + ReLU -> xin (BHWC) [8192,128] ------------------------
__global__ __launch_bounds__(128) void k_conv1x1(const float* __restrict__ pooled,
                                                 const float* __restrict__ cw,
                                                 const float* __restrict__ bg,
                                                 const float* __restrict__ bb,
                                                 const float* __restrict__ bm,
                                                 const float* __restrict__ bv,
                                                 float* __restrict__ xin){
    __shared__ float sp[64];
    int pix = blockIdx.x;                  // 0..8191
    int b = pix >> 12, pl = pix & 4095;
    int t = threadIdx.x;                   // 0..127 = out channel
    if (t < 64) sp[t] = pooled[(b*64 + t)*4096 + pl];
    __syncthreads();
    float scale = bg[t] * rsqrtf(bv[t] + 1e-5f);
    float shift = bb[t] - bm[t]*scale;
    float acc = 0.f;
    #pragma unroll 8
    for (int c = 0; c < 64; ++c) acc += sp[c] * cw[t*64 + c];
    xin[pix*128 + t] = fmaxf(acc*scale + shift, 0.f);
}

// ---- LayerNorm(128) + GEMM [128->512] -> xpart[.,256], z[.,256] -----------
// block = 256 threads, 8 pixels per block
__global__ __launch_bounds__(256) void k_lnproj(const float* __restrict__ xin,
                                                const float* __restrict__ Win,
                                                const float* __restrict__ lng,
                                                const float* __restrict__ lnb,
                                                float* __restrict__ xpart,
                                                float* __restrict__ zbuf){
    __shared__ float sm_raw[8*128];
    __shared__ float sm_h[128*8];          // transposed [c][p]
    int t = threadIdx.x;
    int pix0 = blockIdx.x * 8;
    #pragma unroll
    for (int q = 0; q < 4; ++q) sm_raw[t + 256*q] = xin[pix0*128 + t + 256*q];
    __syncthreads();
    int lane = t & 63, wid = t >> 6;
    #pragma unroll
    for (int pp = 0; pp < 2; ++pp){
        int p = wid*2 + pp;
        float v0 = sm_raw[p*128 + lane];
        float v1 = sm_raw[p*128 + 64 + lane];
        float s = v0 + v1, q = v0*v0 + v1*v1;
        #pragma unroll
        for (int off = 32; off; off >>= 1){ s += __shfl_xor(s, off); q += __shfl_xor(q, off); }
        float mu = s * (1.f/128.f);
        float rs = rsqrtf(q * (1.f/128.f) - mu*mu + 1e-5f);
        sm_h[lane*8 + p]      = (v0 - mu)*rs*lng[lane]    + lnb[lane];
        sm_h[(64+lane)*8 + p] = (v1 - mu)*rs*lng[64+lane] + lnb[64+lane];
    }
    __syncthreads();
    int jl = t & 127, ph = t >> 7;         // 4 j per thread, 4 pixels per thread
    float acc[4][4];
    #pragma unroll
    for (int m = 0; m < 4; ++m)
        #pragma unroll
        for (int q = 0; q < 4; ++q) acc[m][q] = 0.f;
    const float4* hv = reinterpret_cast<const float4*>(sm_h);
    for (int c = 0; c < 128; ++c){
        float4 h4 = hv[c*2 + ph];
        #pragma unroll
        for (int m = 0; m < 4; ++m){
            float w = Win[c*512 + jl + 128*m];
            acc[m][0] += h4.x*w; acc[m][1] += h4.y*w;
            acc[m][2] += h4.z*w; acc[m][3] += h4.w*w;
        }
    }
    #pragma unroll
    for (int m = 0; m < 4; ++m){
        int j = jl + 128*m;
        #pragma unroll
        for (int q = 0; q < 4; ++q){
            int p = ph*4 + q;
            if (j < 256) xpart[(pix0+p)*256 + j]       = acc[m][q];
            else         zbuf [(pix0+p)*256 + (j-256)] = acc[m][q];
        }
    }
}

// ---- depthwise 3x3 + SiLU -> xflat [8192,256] -----------------------------
__global__ __launch_bounds__(256) void k_dw(const float* __restrict__ xpart,
                                            const float* __restrict__ dww,
                                            float* __restrict__ xflat){
    int t = blockIdx.x*256 + threadIdx.x;  // 0..2097151
    int d = t & 255;
    int pl = (t >> 8) & 4095;
    int b = t >> 20;
    int i = pl >> 6, j = pl & 63;
    float acc = 0.f;
    #pragma unroll
    for (int dy = 0; dy < 3; ++dy){
        int ii = i + dy - 1;
        if (ii < 0 || ii > 63) continue;
        #pragma unroll
        for (int dx = 0; dx < 3; ++dx){
            int jj = j + dx - 1;
            if (jj < 0 || jj > 63) continue;
            acc += xpart[((b<<12) + ii*64 + jj)*256 + d] * dww[d*9 + dy*3 + dx];
        }
    }
    xflat[t] = acc * sigm_(acc);
}

// ---- x-projection: proj[pix][k][24] = xflat[pix] @ Wx[k] ------------------
__global__ __launch_bounds__(256) void k_proj(const float* __restrict__ xflat,
                                              const float* __restrict__ Wx,
                                              float* __restrict__ proj){
    int t = blockIdx.x*256 + threadIdx.x;  // 0..393215
    int q = t % 48;                        // k*24 + r
    int pix = t / 48;
    int k = q / 24, r = q % 24;
    const float* xp = xflat + pix*256;
    const float* wp = Wx + k*6144 + r;
    float acc = 0.f;
    #pragma unroll 4
    for (int dd = 0; dd < 256; ++dd) acc += xp[dd] * wp[dd*24];
    proj[t] = acc;
}

// ---- zero fill (ysum) -----------------------------------------------------
__global__ __launch_bounds__(256) void k_zero(float4* __restrict__ p){
    p[blockIdx.x*256 + threadIdx.x] = make_float4(0.f,0.f,0.f,0.f);
}

// ---- scan phase 1: per-chunk decay product P and local state S ------------
// grid (NC, K, B), block 256 (lane = d). k=1 scans backward over original l.
__global__ __launch_bounds__(256) void k_scan1(const float* __restrict__ xflat,
                                               const float* __restrict__ proj,
                                               const float* __restrict__ Wdt,
                                               const float* __restrict__ dtb,
                                               const float* __restrict__ Alog,
                                               float* __restrict__ Pc,
                                               float* __restrict__ Sc){
    int d = threadIdx.x, ch = blockIdx.x, k = blockIdx.y, b = blockIdx.z;
    float A_[NST], wdt[NST];
    #pragma unroll
    for (int n = 0; n < NST; ++n) A_[n] = -__expf(Alog[(k*256 + d)*8 + n]);
    #pragma unroll
    for (int r = 0; r < 8; ++r) wdt[r] = Wdt[(k*8 + r)*256 + d];
    float bias = dtb[k*256 + d];
    float S[NST] = {0,0,0,0,0,0,0,0};
    float dtsum = 0.f;
    for (int i = 0; i < CS; ++i){
        int s = ch*CS + i;
        int pos = k ? (LTOT-1 - s) : s;
        int base = b*LTOT + pos;
        const float* pr = proj + base*48 + k*24;
        float a = bias;
        #pragma unroll
        for (int r = 0; r < 8; ++r) a += pr[r] * wdt[r];
        float dtv = softplus_(a);
        float dx = dtv * xflat[base*256 + d];
        dtsum += dtv;
        #pragma unroll
        for (int n = 0; n < NST; ++n){
            float ab = __expf(dtv * A_[n]);
            S[n] = ab*S[n] + dx*pr[8+n];
        }
    }
    int cbase = (((b*2 + k)*NC + ch)*256 + d)*8;
    #pragma unroll
    for (int n = 0; n < NST; ++n){
        Pc[cbase+n] = __expf(A_[n]*dtsum);
        Sc[cbase+n] = S[n];
    }
}

// ---- scan phase 2: sequential combine across chunks -----------------------
__global__ __launch_bounds__(256) void k_scan2(const float* __restrict__ Pc,
                                               const float* __restrict__ Sc,
                                               float* __restrict__ hinit){
    int t = blockIdx.x*256 + threadIdx.x;  // 0..8191  (b,k,d,n)
    int bk = t >> 11, dn = t & 2047;
    float h = 0.f;
    #pragma unroll 8
    for (int c = 0; c < NC; ++c){
        int idx = (bk*NC + c)*2048 + dn;
        hinit[idx] = h;
        h = Pc[idx]*h + Sc[idx];
    }
}

// ---- scan phase 3: rescan with true init, emit y (atomicAdd into ysum) ----
__global__ __launch_bounds__(256) void k_scan3(const float* __restrict__ xflat,
                                               const float* __restrict__ proj,
                                               const float* __restrict__ Wdt,
                                               const float* __restrict__ dtb,
                                               const float* __restrict__ Alog,
                                               const float* __restrict__ Dp,
                                               const float* __restrict__ hinit,
                                               float* __restrict__ ysum){
    int d = threadIdx.x, ch = blockIdx.x, k = blockIdx.y, b = blockIdx.z;
    float A_[NST], wdt[NST], h[NST];
    #pragma unroll
    for (int n = 0; n < NST; ++n) A_[n] = -__expf(Alog[(k*256 + d)*8 + n]);
    #pragma unroll
    for (int r = 0; r < 8; ++r) wdt[r] = Wdt[(k*8 + r)*256 + d];
    float bias = dtb[k*256 + d];
    int cbase = (((b*2 + k)*NC + ch)*256 + d)*8;
    #pragma unroll
    for (int n = 0; n < NST; ++n) h[n] = hinit[cbase+n];
    float Dd = Dp[k*256 + d];
    for (int i = 0; i < CS; ++i){
        int s = ch*CS + i;
        int pos = k ? (LTOT-1 - s) : s;
        int base = b*LTOT + pos;
        const float* pr = proj + base*48 + k*24;
        float a = bias;
        #pragma unroll
        for (int r = 0; r < 8; ++r) a += pr[r] * wdt[r];
        float dtv = softplus_(a);
        float xv = xflat[base*256 + d];
        float dx = dtv * xv;
        float y = xv * Dd;
        #pragma unroll
        for (int n = 0; n < NST; ++n){
            float ab = __expf(dtv * A_[n]);
            h[n] = ab*h[n] + dx*pr[8+n];
            y += h[n]*pr[16+n];
        }
        atomicAdd(&ysum[base*256 + d], y);
    }
}

// ---- final: LN(256) + gate*silu(z) + GEMM [256->128] + residual -> BHWC ---
// block = 256 threads, 8 pixels per block
__global__ __launch_bounds__(256) void k_final(const float* __restrict__ ysum,
                                               const float* __restrict__ zbuf,
                                               const float* __restrict__ xin,
                                               const float* __restrict__ ong,
                                               const float* __restrict__ onb,
                                               const float* __restrict__ Wout,
                                               float* __restrict__ obhwc){
    __shared__ float sm_ly[256*8];         // [dd][p]
    __shared__ float smp[8][4][2];
    __shared__ float smstat[8][2];
    int t = threadIdx.x;
    int pix0 = blockIdx.x * 8;
    int lane = t & 63, wid = t >> 6;
    float v[8];
    #pragma unroll
    for (int p = 0; p < 8; ++p){
        v[p] = ysum[(pix0+p)*256 + t];
        float s = v[p], q = v[p]*v[p];
        #pragma unroll
        for (int off = 32; off; off >>= 1){ s += __shfl_xor(s, off); q += __shfl_xor(q, off); }
        if (lane == 0){ smp[p][wid][0] = s; smp[p][wid][1] = q; }
    }
    __syncthreads();
    if (t < 8){
        float s = smp[t][0][0]+smp[t][1][0]+smp[t][2][0]+smp[t][3][0];
        float q = smp[t][0][1]+smp[t][1][1]+smp[t][2][1]+smp[t][3][1];
        float mu = s * (1.f/256.f);
        float var = q * (1.f/256.f) - mu*mu;
        smstat[t][0] = mu;
        smstat[t][1] = rsqrtf(var + 1e-5f);
    }
    __syncthreads();
    float g = ong[t], be = onb[t];
    #pragma unroll
    for (int p = 0; p < 8; ++p){
        float zl = zbuf[(pix0+p)*256 + t];
        float ln = (v[p] - smstat[p][0]) * smstat[p][1] * g + be;
        sm_ly[t*8 + p] = ln * (zl * sigm_(zl));
    }
    __syncthreads();
    int o = t & 127, ph = t >> 7;
    float acc[4] = {0.f,0.f,0.f,0.f};
    const float4* lyv = reinterpret_cast<const float4*>(sm_ly);
    for (int dd = 0; dd < 256; ++dd){
        float w = Wout[dd*128 + o];
        float4 l4 = lyv[dd*2 + ph];
        acc[0] += l4.x*w; acc[1] += l4.y*w; acc[2] += l4.z*w; acc[3] += l4.w*w;
    }
    #pragma unroll
    for (int q = 0; q < 4; ++q){
        int p = ph*4 + q;
        obhwc[(pix0+p)*128 + o] = acc[q] + xin[(pix0+p)*128 + o];
    }
}

// ---- transpose BHWC -> BCHW, duplicate into tuple -------------------------
__global__ __launch_bounds__(256) void k_tr(const float* __restrict__ obhwc,
                                            float* __restrict__ out){
    __shared__ float tile[32][33];
    int tx = threadIdx.x, ty = threadIdx.y;
    int x0 = blockIdx.x*32, c0 = blockIdx.y*32, b = blockIdx.z;
    #pragma unroll
    for (int r = ty; r < 32; r += 8)
        tile[r][tx] = obhwc[(b*4096 + x0 + r)*128 + c0 + tx];
    __syncthreads();
    #pragma unroll
    for (int r = ty; r < 32; r += 8){
        float vv = tile[tx][r];
        int oidx = (b*128 + c0 + r)*4096 + x0 + tx;
        out[oidx] = vv;
        out[1048576 + oidx] = vv;
    }
}

// ---------------------------------------------------------------------------
extern "C" void kernel_launch(void* const* d_in, const int* in_sizes, int n_in,
                              void* d_out, int out_size, void* d_ws, size_t ws_size,
                              hipStream_t stream){
    const float* x      = (const float*)d_in[0];
    const float* conv_w = (const float*)d_in[1];
    const float* bng    = (const float*)d_in[2];
    const float* bnb    = (const float*)d_in[3];
    const float* bnm    = (const float*)d_in[4];
    const float* bnv    = (const float*)d_in[5];
    const float* lng    = (const float*)d_in[6];
    const float* lnb    = (const float*)d_in[7];
    const float* Win    = (const float*)d_in[8];
    const float* dww    = (const float*)d_in[9];
    const float* Wx     = (const float*)d_in[10];
    const float* Wdt    = (const float*)d_in[11];
    const float* dtb    = (const float*)d_in[12];
    const float* Alog   = (const float*)d_in[13];
    const float* Dp     = (const float*)d_in[14];
    const float* ong    = (const float*)d_in[15];
    const float* onb    = (const float*)d_in[16];
    const float* Wout   = (const float*)d_in[17];
    float* out = (float*)d_out;

    float* w = (float*)d_ws;
    float* pooled = w;  w += 524288;    // [2,64,64,64]
    float* xin    = w;  w += 1048576;   // [8192,128]
    float* xpart  = w;  w += 2097152;   // [8192,256]  (reused as obhwc)
    float* zbuf   = w;  w += 2097152;   // [8192,256]
    float* xflat  = w;  w += 2097152;   // [8192,256]
    float* proj   = w;  w += 393216;    // [8192,2,24]
    float* Pc     = w;  w += 1048576;   // [2,2,NC,256,8]
    float* Sc     = w;  w += 1048576;
    float* hinit  = w;  w += 1048576;
    float* ysum   = w;  w += 2097152;   // [8192,256]
    float* obhwc  = xpart;              // alias: xpart dead after k_dw

    k_pool   <<<2048, 256, 0, stream>>>(x, pooled);
    k_conv1x1<<<8192, 128, 0, stream>>>(pooled, conv_w, bng, bnb, bnm, bnv, xin);
    k_lnproj <<<1024, 256, 0, stream>>>(xin, Win, lng, lnb, xpart, zbuf);
    k_dw     <<<8192, 256, 0, stream>>>(xpart, dww, xflat);
    k_proj   <<<1536, 256, 0, stream>>>(xflat, Wx, proj);
    k_zero   <<<2048, 256, 0, stream>>>((float4*)ysum);
    k_scan1  <<<dim3(NC,2,2), 256, 0, stream>>>(xflat, proj, Wdt, dtb, Alog, Pc, Sc);
    k_scan2  <<<32,   256, 0, stream>>>(Pc, Sc, hinit);
    k_scan3  <<<dim3(NC,2,2), 256, 0, stream>>>(xflat, proj, Wdt, dtb, Alog, Dp, hinit, ysum);
    k_final  <<<1024, 256, 0, stream>>>(ysum, zbuf, xin, ong, onb, Wout, obhwc);
    k_tr     <<<dim3(128,4,2), dim3(32,8), 0, stream>>>(obhwc, out);
}